// Round 1
// baseline (83.984 us; speedup 1.0000x reference)
//
#include <hip/hip_runtime.h>

#define HH 512
#define WW 512
#define NB 2
#define NP 4
#define NK 17
#define NS (NP*NK)   // 68

// size_ranges from the module, [K][2]
__constant__ float c_sr[NK*2] = {
  0.10f,0.20f, 0.10f,0.20f, 0.10f,0.20f, 0.10f,0.20f, 0.10f,0.20f,
  0.15f,0.30f, 0.15f,0.30f,
  0.10f,0.25f, 0.10f,0.25f,
  0.10f,0.20f, 0.10f,0.20f,
  0.20f,0.40f, 0.20f,0.40f,
  0.15f,0.30f, 0.15f,0.30f,
  0.10f,0.25f, 0.10f,0.25f
};

// ws float layout:
//   [0,153)            : sigmoid texture, K*9
//   [160,160+4*NB*NS)  : raw params float4 [B][S] = {fx, ox, oy, alpha*valid}
//   int [704..705]     : per-batch compacted count
//   [720,720+4*NB*NS)  : compacted params float4 [B][S] (s-order preserved)
//   int [1264,1400)    : compacted tex offsets (k*9)

__global__ __launch_bounds__(256) void setup_k(
    const float* __restrict__ kpts,   // [B,P,K,3]
    const float* __restrict__ bbox,   // [B,P,4]
    const float* __restrict__ gtex,   // [K,1,3,3]
    const float* __restrict__ slog,   // [K]
    const float* __restrict__ alog,   // [K]
    float* __restrict__ ws,
    float* __restrict__ alphas_out)   // d_out tail, [K]
{
  int tid = threadIdx.x;
  if (tid < NK*9) {
    ws[tid] = 1.0f / (1.0f + expf(-10.0f * gtex[tid]));
  }
  if (tid < NK) {
    alphas_out[tid] = 1.0f / (1.0f + expf(-alog[tid]));
  }
  if (tid < NB*NS) {
    int b = tid / NS, s = tid % NS, p = s / NK, k = s % NK;
    const float* kp = kpts + ((b*NP + p)*NK + k)*3;
    float x = kp[0], y = kp[1], v = kp[2];
    float pw = bbox[(b*NP + p)*4 + 2];
    float sig   = 1.0f / (1.0f + expf(-slog[k]));
    float sc    = c_sr[2*k] + sig * (c_sr[2*k+1] - c_sr[2*k]);
    float alpha = 1.0f / (1.0f + expf(-alog[k]));
    float valid = (v != 0.0f && pw > 1.0f) ? 1.0f : 0.0f;
    float pps = fmaxf(sc * pw, 3.0f);
    // ix = 15*gx + 14.5, gx = (2j+1-2x)/pps  ->  ix = fx*j + ox
    float fx = 30.0f / pps;
    float4 pr;
    pr.x = fx;
    pr.y = fx * (0.5f - x) + 14.5f;
    pr.z = fx * (0.5f - y) + 14.5f;
    pr.w = alpha * valid;
    reinterpret_cast<float4*>(ws + 160)[tid] = pr;
  }
  __syncthreads();
  if (tid < NB) {  // serial order-preserving compaction, trivial cost
    const float4* raw = reinterpret_cast<const float4*>(ws + 160) + tid*NS;
    float4* cp = reinterpret_cast<float4*>(ws + 720) + tid*NS;
    int* ck = reinterpret_cast<int*>(ws) + 1264 + tid*NS;
    int cnt = 0;
    for (int s = 0; s < NS; ++s) {
      float4 pr = raw[s];
      if (pr.w > 0.0f) {
        cp[cnt] = pr;
        ck[cnt] = (s % NK) * 9;
        cnt++;
      }
    }
    reinterpret_cast<int*>(ws)[704 + tid] = cnt;
  }
}

__global__ __launch_bounds__(256) void comp_k(
    const float* __restrict__ images, const float* __restrict__ ws,
    float* __restrict__ out)
{
  __shared__ float  s_tex[NK*9];
  __shared__ float4 s_par[NS];
  __shared__ int    s_kid[NS];
  __shared__ float4 s_cp[NS];
  __shared__ int    s_ck[NS];
  __shared__ int    s_cnt;

  int tid = threadIdx.x;
  int gid = blockIdx.x * 256 + tid;
  int b   = gid >> 18;             // H*W = 2^18
  int pix = gid & (HH*WW - 1);
  int cnt_g = reinterpret_cast<const int*>(ws)[704 + b];

  if (tid < NK*9) s_tex[tid] = ws[tid];
  if (tid < NS) {
    s_par[tid] = reinterpret_cast<const float4*>(ws + 720)[b*NS + tid];
    s_kid[tid] = reinterpret_cast<const int*>(ws)[1264 + b*NS + tid];
  }
  __syncthreads();

  int i = pix >> 9;        // row, uniform within block
  int j = pix & (WW - 1);

  // Wave-0 geometric cull: block = one row, columns [j0, j0+255]
  if (tid < 64) {
    float rowf  = (float)i;
    float jminf = (float)((blockIdx.x & 1) * 256);
    float jmaxf = jminf + 255.0f;
    bool pred = false;
    if (tid < cnt_g) {
      float4 pr = s_par[tid];
      float iy  = fmaf(pr.x, rowf,  pr.z);
      float ixa = fmaf(pr.x, jminf, pr.y);
      float ixb = fmaf(pr.x, jmaxf, pr.y);
      pred = (iy > -1.0f) && (iy < 30.0f) && (ixb > -1.0f) && (ixa < 30.0f);
    }
    unsigned long long m1 = __ballot(pred);
    int rank = __popcll(m1 & ((1ull << tid) - 1ull));
    if (pred) { s_cp[rank] = s_par[tid]; s_ck[rank] = s_kid[tid]; }
    int base = __popcll(m1);
    bool pred2 = false;
    int s2 = 64 + tid;
    if (s2 < cnt_g) {   // only tid<4 possible (cnt<=68)
      float4 pr = s_par[s2];
      float iy  = fmaf(pr.x, rowf,  pr.z);
      float ixa = fmaf(pr.x, jminf, pr.y);
      float ixb = fmaf(pr.x, jmaxf, pr.y);
      pred2 = (iy > -1.0f) && (iy < 30.0f) && (ixb > -1.0f) && (ixa < 30.0f);
    }
    unsigned long long m2 = __ballot(pred2);
    int rank2 = base + __popcll(m2 & ((1ull << tid) - 1ull));
    if (pred2) { s_cp[rank2] = s_par[s2]; s_ck[rank2] = s_kid[s2]; }
    if (tid == 0) s_cnt = base + __popcll(m2);
  }
  __syncthreads();
  int nact = s_cnt;

  const float* ib = images + b*(3*HH*WW) + pix;
  float r0 = ib[0];
  float r1 = ib[HH*WW];
  float r2 = ib[2*HH*WW];
  float jf = (float)j, if_ = (float)i;

  for (int n = 0; n < nact; ++n) {
    float4 pr = s_cp[n];
    float ix = fmaf(pr.x, jf,  pr.y);
    float iy = fmaf(pr.x, if_, pr.z);
    if (ix > -1.0f && ix < 30.0f && iy > -1.0f && iy < 30.0f) {
      int toff = s_ck[n];
      float ix0f = floorf(ix), iy0f = floorf(iy);
      float wx1 = ix - ix0f, wy1 = iy - iy0f;
      float wx0 = 1.0f - wx1, wy0 = 1.0f - wy1;
      int x0 = (int)ix0f, y0 = (int)iy0f;
      int x1 = x0 + 1, y1 = y0 + 1;
      bool vx0 = (unsigned)x0 < 30u;
      bool vx1 = (unsigned)x1 < 30u;
      bool vy0 = (unsigned)y0 < 30u;
      bool vy1 = (unsigned)y1 < 30u;
      // nearest-upsample: 30x30 texel (yy,xx) -> 3x3 texel (yy/10, xx/10)
      int cx0 = x0 >= 20 ? 2 : (x0 >= 10 ? 1 : 0);
      int cx1 = x1 >= 20 ? 2 : (x1 >= 10 ? 1 : 0);
      int cy0 = y0 >= 20 ? 6 : (y0 >= 10 ? 3 : 0);  // *3 folded in
      int cy1 = y1 >= 20 ? 6 : (y1 >= 10 ? 3 : 0);
      const float* tk = s_tex + toff;
      float mw = 0.0f, pv = 0.0f, w;
      w = (vx0 && vy0) ? wy0*wx0 : 0.0f; mw += w; pv = fmaf(w, tk[cy0+cx0], pv);
      w = (vx1 && vy0) ? wy0*wx1 : 0.0f; mw += w; pv = fmaf(w, tk[cy0+cx1], pv);
      w = (vx0 && vy1) ? wy1*wx0 : 0.0f; mw += w; pv = fmaf(w, tk[cy1+cx0], pv);
      w = (vx1 && vy1) ? wy1*wx1 : 0.0f; mw += w; pv = fmaf(w, tk[cy1+cx1], pv);
      float m  = mw * pr.w;     // mw * alpha * valid
      float om = 1.0f - m;
      float pm = pv * m;
      r0 = fmaf(r0, om, pm);
      r1 = fmaf(r1, om, pm);
      r2 = fmaf(r2, om, pm);
    }
  }
  float* ob = out + b*(3*HH*WW) + pix;
  ob[0]        = r0;
  ob[HH*WW]    = r1;
  ob[2*HH*WW]  = r2;
}

extern "C" void kernel_launch(void* const* d_in, const int* in_sizes, int n_in,
                              void* d_out, int out_size, void* d_ws, size_t ws_size,
                              hipStream_t stream) {
  const float* images = (const float*)d_in[0];
  const float* kpts   = (const float*)d_in[1];
  const float* bbox   = (const float*)d_in[2];
  const float* gtex   = (const float*)d_in[3];
  const float* slog   = (const float*)d_in[4];
  const float* alog   = (const float*)d_in[5];
  float* outp = (float*)d_out;
  float* ws   = (float*)d_ws;
  float* alphas_out = outp + NB*3*HH*WW;   // second tuple element

  hipLaunchKernelGGL(setup_k, dim3(1), dim3(256), 0, stream,
                     kpts, bbox, gtex, slog, alog, ws, alphas_out);
  hipLaunchKernelGGL(comp_k, dim3((NB*HH*WW)/256), dim3(256), 0, stream,
                     images, ws, outp);
}

// Round 4
// 69.888 us; speedup vs baseline: 1.2017x; 1.2017x over previous
//
#include <hip/hip_runtime.h>

#define HH 512
#define WW 512
#define NB 2
#define NP 4
#define NK 17
#define NS (NP*NK)   // 68

// size_ranges from the module, [K][2]
__constant__ float c_sr[NK*2] = {
  0.10f,0.20f, 0.10f,0.20f, 0.10f,0.20f, 0.10f,0.20f, 0.10f,0.20f,
  0.15f,0.30f, 0.15f,0.30f,
  0.10f,0.25f, 0.10f,0.25f,
  0.10f,0.20f, 0.10f,0.20f,
  0.20f,0.40f, 0.20f,0.40f,
  0.15f,0.30f, 0.15f,0.30f,
  0.10f,0.25f, 0.10f,0.25f
};

// Single fused kernel: per-block prologue recomputes the 68 patch affine
// params (L2-resident input reads, 2 expf each) and the 17x3x3 sigmoid
// texture, then wave-0 does an order-preserving geometric cull for this
// block's 256-pixel row segment, then each thread composites its pixel.
__global__ __launch_bounds__(256) void fused_k(
    const float* __restrict__ images,
    const float* __restrict__ kpts,   // [B,P,K,3]
    const float* __restrict__ bbox,   // [B,P,4]
    const float* __restrict__ gtex,   // [K,1,3,3]
    const float* __restrict__ slog,   // [K]
    const float* __restrict__ alog,   // [K]
    float* __restrict__ out,
    float* __restrict__ alphas_out)   // d_out tail, [K]
{
  __shared__ float  s_tex[NK*9];
  __shared__ float4 s_par[NS];
  __shared__ float4 s_cp[NS];
  __shared__ int    s_ck[NS];
  __shared__ int    s_cnt;

  int tid = threadIdx.x;
  int gid = blockIdx.x * 256 + tid;
  int b   = gid >> 18;             // H*W = 2^18
  int pix = gid & (HH*WW - 1);

  // texture sigmoid: threads 0..152 (waves 0..2)
  if (tid < NK*9) {
    s_tex[tid] = 1.0f / (1.0f + __expf(-10.0f * gtex[tid]));
  }
  // alphas output (second tuple element): block 0 only
  if (blockIdx.x == 0 && tid >= 160 && tid < 160 + NK) {
    int k = tid - 160;
    alphas_out[k] = 1.0f / (1.0f + expf(-alog[k]));
  }
  // patch params: threads 188..255 (wave 3 + top of wave 2, disjoint from texture)
  if (tid >= 188) {
    int s = tid - 188;             // [0,68)
    int p = s / NK, k = s - p*NK;
    const float* kp = kpts + ((b*NP + p)*NK + k)*3;
    float x = kp[0], y = kp[1], v = kp[2];
    float pw = bbox[(b*NP + p)*4 + 2];
    float sig   = 1.0f / (1.0f + expf(-slog[k]));
    float sc    = c_sr[2*k] + sig * (c_sr[2*k+1] - c_sr[2*k]);
    float alpha = 1.0f / (1.0f + expf(-alog[k]));
    float valid = (v != 0.0f && pw > 1.0f) ? 1.0f : 0.0f;
    float pps = fmaxf(sc * pw, 3.0f);
    // patch-space coord: ix = fx*j + ox  (fx = 30/pps)
    float fx = 30.0f / pps;
    float4 pr;
    pr.x = fx;
    pr.y = fx * (0.5f - x) + 14.5f;
    pr.z = fx * (0.5f - y) + 14.5f;
    pr.w = alpha * valid;
    s_par[s] = pr;
  }
  __syncthreads();

  int i = pix >> 9;        // row, uniform within block
  int j = pix & (WW - 1);

  // Wave-0 order-preserving cull: block = one row, columns [j0, j0+255].
  // Validity (pr.w>0) folded into the predicate.
  if (tid < 64) {
    float rowf  = (float)i;
    float jminf = (float)((blockIdx.x & 1) * 256);
    float jmaxf = jminf + 255.0f;
    float4 pr = s_par[tid];
    float iy  = fmaf(pr.x, rowf,  pr.z);
    float ixa = fmaf(pr.x, jminf, pr.y);
    float ixb = fmaf(pr.x, jmaxf, pr.y);
    bool pred = (pr.w > 0.0f) && (iy > -1.0f) && (iy < 30.0f)
              && (ixb > -1.0f) && (ixa < 30.0f);
    unsigned long long m1 = __ballot(pred);
    int rank = __popcll(m1 & ((1ull << tid) - 1ull));
    int kk = (int)((unsigned)tid % (unsigned)NK); // tid<64: k = tid%17
    if (pred) { s_cp[rank] = pr; s_ck[rank] = kk*9; }
    int base = __popcll(m1);
    bool pred2 = false;
    int s2 = 64 + tid;
    if (s2 < NS) {   // only tid<4
      float4 q = s_par[s2];
      float iy2  = fmaf(q.x, rowf,  q.z);
      float ixa2 = fmaf(q.x, jminf, q.y);
      float ixb2 = fmaf(q.x, jmaxf, q.y);
      pred2 = (q.w > 0.0f) && (iy2 > -1.0f) && (iy2 < 30.0f)
            && (ixb2 > -1.0f) && (ixa2 < 30.0f);
    }
    unsigned long long m2 = __ballot(pred2);
    int rank2 = base + __popcll(m2 & ((1ull << tid) - 1ull));
    if (pred2) { s_cp[rank2] = s_par[s2]; s_ck[rank2] = ((s2 - 51) % NK) * 9; }
    if (tid == 0) s_cnt = base + __popcll(m2);
  }
  __syncthreads();
  int nact = s_cnt;

  const float* ib = images + b*(3*HH*WW) + pix;
  float r0 = ib[0];
  float r1 = ib[HH*WW];
  float r2 = ib[2*HH*WW];
  float jf = (float)j, if_ = (float)i;

  for (int n = 0; n < nact; ++n) {
    float4 pr = s_cp[n];
    float ix = fmaf(pr.x, jf,  pr.y);
    float iy = fmaf(pr.x, if_, pr.z);
    if (ix > -1.0f && ix < 30.0f && iy > -1.0f && iy < 30.0f) {
      int toff = s_ck[n];
      float ix0f = floorf(ix), iy0f = floorf(iy);
      float wx1 = ix - ix0f, wy1 = iy - iy0f;
      float wx0 = 1.0f - wx1, wy0 = 1.0f - wy1;
      int x0 = (int)ix0f, y0 = (int)iy0f;
      int x1 = x0 + 1, y1 = y0 + 1;
      bool vx0 = (unsigned)x0 < 30u;
      bool vx1 = (unsigned)x1 < 30u;
      bool vy0 = (unsigned)y0 < 30u;
      bool vy1 = (unsigned)y1 < 30u;
      // nearest-upsample: 30x30 texel (yy,xx) -> 3x3 texel (yy/10, xx/10)
      int cx0 = x0 >= 20 ? 2 : (x0 >= 10 ? 1 : 0);
      int cx1 = x1 >= 20 ? 2 : (x1 >= 10 ? 1 : 0);
      int cy0 = y0 >= 20 ? 6 : (y0 >= 10 ? 3 : 0);  // *3 folded in
      int cy1 = y1 >= 20 ? 6 : (y1 >= 10 ? 3 : 0);
      const float* tk = s_tex + toff;
      float mw = 0.0f, pv = 0.0f, w;
      w = (vx0 && vy0) ? wy0*wx0 : 0.0f; mw += w; pv = fmaf(w, tk[cy0+cx0], pv);
      w = (vx1 && vy0) ? wy0*wx1 : 0.0f; mw += w; pv = fmaf(w, tk[cy0+cx1], pv);
      w = (vx0 && vy1) ? wy1*wx0 : 0.0f; mw += w; pv = fmaf(w, tk[cy1+cx0], pv);
      w = (vx1 && vy1) ? wy1*wx1 : 0.0f; mw += w; pv = fmaf(w, tk[cy1+cx1], pv);
      float m  = mw * pr.w;     // mw * alpha * valid
      float om = 1.0f - m;
      float pm = pv * m;
      r0 = fmaf(r0, om, pm);
      r1 = fmaf(r1, om, pm);
      r2 = fmaf(r2, om, pm);
    }
  }
  float* ob = out + b*(3*HH*WW) + pix;
  ob[0]        = r0;
  ob[HH*WW]    = r1;
  ob[2*HH*WW]  = r2;
}

extern "C" void kernel_launch(void* const* d_in, const int* in_sizes, int n_in,
                              void* d_out, int out_size, void* d_ws, size_t ws_size,
                              hipStream_t stream) {
  const float* images = (const float*)d_in[0];
  const float* kpts   = (const float*)d_in[1];
  const float* bbox   = (const float*)d_in[2];
  const float* gtex   = (const float*)d_in[3];
  const float* slog   = (const float*)d_in[4];
  const float* alog   = (const float*)d_in[5];
  float* outp = (float*)d_out;
  float* alphas_out = outp + NB*3*HH*WW;   // second tuple element

  hipLaunchKernelGGL(fused_k, dim3((NB*HH*WW)/256), dim3(256), 0, stream,
                     images, kpts, bbox, gtex, slog, alog, outp, alphas_out);
}